// Round 6
// baseline (241.809 us; speedup 1.0000x reference)
//
#include <hip/hip_runtime.h>

// TELIF: temporal-encoding LIF neuron scan.
// tx: [T, B, N] fp32, TE: [N, T] fp32, out ty: [T, B, N] fp32 (0/1 spikes).
// T=512, B=64, N=1024. One thread per (b,n) sequence; sequential over t.
//
// v6b: v6 with the compile fix -- __builtin_nontemporal_store requires a
// native clang vector (ext_vector_type), not HIP's float4 struct.
//
// v6: 1 KB granules BOTH directions at full wave count (1024 waves).
//   Evidence: v1/v4/v5 (256 B load+store granules, any pipeline depth) all
//   ~82 us / 2.5 TB/s -- depth is not the lever. v3 (fat loads, thin stores)
//   identical -- loads are not the lever alone. fillBufferAligned: 6.7 TB/s
//   at the same occupancy with dwordx4 -> granule is the lever, for BOTH
//   streams. Structure: 256 blocks x 256 thr (1 block/CU, 4 waves).
//   - Loads: each wave stages 4 t-rows per 16-t chunk via global_load_lds
//     dwordx4 (1 KB/instr, 1 row/instr) into a 4-slot LDS ring, depth 3
//     chunks ahead, counted vmcnt ladder (never 0 mid-loop), raw s_barrier.
//   - Compute: x via ds_read_b32 (tid column, 2-way bank = free), exact
//     reference arithmetic (fp contract off), y -> ystage[u][tid].
//   - Stores: after lgkmcnt(0)+barrier, wave w reads rows 4w+j of ystage
//     as 16B (contiguous row, conflict-free) and writes 1 KB
//     global_store_dwordx4 (nontemporal) per row.
//   TE is register-prefetched one chunk ahead, issued FIRST in each round
//   so the compiler's implicit wait for it at the rotate sits BEHIND no
//   chunk loads in the in-order vmcnt stream (doesn't drain the pipeline).
//   LDS: 4*16*256*4 (ring 64 KiB) + 16*256*4 (ystage 16 KiB) = 80 KiB.

#define T_STEPS 512
#define BATCH   64
#define NNEUR   1024
#define BN      (BATCH * NNEUR)
#define UCHUNK  16
#define NCHUNK  (T_STEPS / UCHUNK)   // 32
#define NSLOT   4
#define DEPTH   3
#define BT      256

typedef float f32x4 __attribute__((ext_vector_type(4)));

__global__ __launch_bounds__(BT) void telif_kernel(
    const float* __restrict__ tx, const float* __restrict__ TE,
    float* __restrict__ out)
{
    // Reference is validated against fp32 elementwise ops with a hard
    // (v > th) threshold: forbid FMA contraction so rounding matches exactly.
#pragma clang fp contract(off)

    __shared__ float buf[NSLOT][UCHUNK][BT];   // tx staging ring, 64 KiB
    __shared__ float ystage[UCHUNK][BT];       // y transpose buffer, 16 KiB

    const int tid = threadIdx.x;
    const int wv  = tid >> 6;                  // wave 0..3
    const int ln  = tid & 63;                  // lane
    const int blockBase = blockIdx.x * BT;     // first flat (b*N+n) index
    const int flat = blockBase + tid;
    const int n = flat & (NNEUR - 1);
    const float* tep = TE + n * T_STEPS;       // contiguous along t

    float v  = 0.0f;   // REST
    float y  = 0.0f;
    float th = 0.3f;   // THRESHOLD

    float tc[UCHUNK], tn[UCHUNK];              // TE double buffer

    // Per-lane global source for 1 KB row loads: lane l covers floats
    // [4l, 4l+4) of the block's 256-float span of a t-row.
    const float* gld = tx + blockBase + ln * 4;

    auto issue_chunk = [&](int k) {
        const int slot = k & (NSLOT - 1);
#pragma unroll
        for (int j = 0; j < 4; ++j) {          // wave wv stages rows 4wv..4wv+3
            const int row = 4 * wv + j;
            const float* g = gld + (size_t)(k * UCHUNK + row) * BN;
            __builtin_amdgcn_global_load_lds(
                (const __attribute__((address_space(1))) void*)g,
                (__attribute__((address_space(3))) void*)&buf[slot][row][0],
                16, 0, 0);
        }
    };

    // Prologue issue order (pinned): L0 L1 L2 | T0. The vmcnt ladder below
    // is computed from this exact order.
    issue_chunk(0);
    issue_chunk(1);
    issue_chunk(2);
    __builtin_amdgcn_sched_barrier(0);
#pragma unroll
    for (int u = 0; u < UCHUNK; u += 4) {
        float4 f = *reinterpret_cast<const float4*>(tep + u);
        tc[u] = f.x; tc[u + 1] = f.y; tc[u + 2] = f.z; tc[u + 3] = f.w;
    }
    __builtin_amdgcn_sched_barrier(0);

#pragma unroll 1
    for (int r = 0; r < NCHUNK; ++r) {
        const int t0 = r * UCHUNK;

        // Round vmem stream (pinned by sched_barriers):
        //   [T_{r+1} (4)] [L_{r+DEPTH} (4)] WAIT BAR compute BAR [S_r (4)]
        // TE first so its implicit wait at the rotate precedes the L group.
        if (r + 1 < NCHUNK) {
#pragma unroll
            for (int u = 0; u < UCHUNK; u += 4) {
                float4 f = *reinterpret_cast<const float4*>(tep + t0 + UCHUNK + u);
                tn[u] = f.x; tn[u+1] = f.y; tn[u+2] = f.z; tn[u+3] = f.w;
            }
        }
        __builtin_amdgcn_sched_barrier(0);

        if (r + DEPTH < NCHUNK) issue_chunk(r + DEPTH);
        __builtin_amdgcn_sched_barrier(0);

        // Counted wait for chunk r's loads (issued DEPTH rounds ago).
        // Outstanding-after-target, from the pinned stream order:
        //   r==0:20  r==1:28  r in [2,28]:36  r==29:32(->20 safe)
        //   r==30:28  r==31:20
        if (r >= 2 && r <= 28) {
            asm volatile("s_waitcnt vmcnt(36)" ::: "memory");
        } else if (r == 1 || r == 30) {
            asm volatile("s_waitcnt vmcnt(28)" ::: "memory");
        } else {  // r==0, 29, 31 (29's exact bound is 32; 20 is safe-strict)
            asm volatile("s_waitcnt vmcnt(20)" ::: "memory");
        }
        __builtin_amdgcn_sched_barrier(0);
        __builtin_amdgcn_s_barrier();          // chunk r visible to all waves

        // Compute 16 steps. Exact op order of the reference:
        //   th = th + v*te - (th - THRESHOLD)*BETA
        //   v  = v*DECAY*(1-y) + x
        //   y  = (v > th)
        const float* xcol = &buf[r & (NSLOT - 1)][0][tid];
#pragma unroll
        for (int u = 0; u < UCHUNK; ++u) {
            float x    = xcol[u * BT];         // ds_read_b32, 2 lanes/bank: free
            float a    = v * tc[u];
            float bsum = th + a;
            float c    = th - 0.3f;
            float d    = c * 0.02f;
            th = bsum - d;
            float e  = v * 0.2f;
            float f1 = 1.0f - y;
            float g  = e * f1;
            v = g + x;
            y = (v > th) ? 1.0f : 0.0f;
            ystage[u][tid] = y;                // ds_write_b32, 2 lanes/bank
        }
        asm volatile("s_waitcnt lgkmcnt(0)" ::: "memory");  // ystage written
        __builtin_amdgcn_sched_barrier(0);
        __builtin_amdgcn_s_barrier();          // ystage visible to all waves

        // Store phase: wave wv writes rows 4wv..4wv+3 as 1 KB dwordx4.
#pragma unroll
        for (int j = 0; j < 4; ++j) {
            const int row = 4 * wv + j;
            f32x4 yv = *reinterpret_cast<const f32x4*>(&ystage[row][ln * 4]);
            __builtin_nontemporal_store(yv,
                reinterpret_cast<f32x4*>(out + (size_t)(t0 + row) * BN
                                             + blockBase + ln * 4));
        }
        __builtin_amdgcn_sched_barrier(0);

        // Rotate TE buffer (register moves).
#pragma unroll
        for (int u = 0; u < UCHUNK; ++u) tc[u] = tn[u];
    }
}

extern "C" void kernel_launch(void* const* d_in, const int* in_sizes, int n_in,
                              void* d_out, int out_size, void* d_ws, size_t ws_size,
                              hipStream_t stream) {
    const float* tx = (const float*)d_in[0];  // [T, B, N]
    const float* TE = (const float*)d_in[1];  // [N, T]
    float* out = (float*)d_out;               // [T, B, N]
    telif_kernel<<<BN / BT, BT, 0, stream>>>(tx, TE, out);
}